// Round 8
// baseline (9709.641 us; speedup 1.0000x reference)
//
#include <hip/hip_runtime.h>

#define Tn 512
#define Bn 256
#define Hn 512
#define INn 512
#define TPB 512

typedef __attribute__((ext_vector_type(8))) short bf16x8;
typedef __attribute__((ext_vector_type(4))) float f32x4;

__device__ __forceinline__ unsigned short f2bf(float f) {
  unsigned int u = __float_as_uint(f);
  unsigned int r = (u + 0x7fffu + ((u >> 16) & 1u)) >> 16;
  return (unsigned short)r;
}
__device__ __forceinline__ float bf2f(unsigned short u) {
  return __uint_as_float(((unsigned int)u) << 16);
}

__device__ __forceinline__ float sigm(float x) { return 1.0f / (1.0f + __expf(-x)); }
__device__ __forceinline__ float tanh_f(float x) { return 2.0f / (1.0f + __expf(-2.0f * x)) - 1.0f; }

__device__ __forceinline__ bf16x8 ld8(const unsigned short* p) {
  return *reinterpret_cast<const bf16x8*>(p);
}

// ---- agent-scope (LLC) relaxed ops — the ONLY cross-block medium (r3/r4-proven) ----
__device__ __forceinline__ unsigned long long ald8(const unsigned short* p) {
  return __hip_atomic_load((const unsigned long long*)p, __ATOMIC_RELAXED,
                           __HIP_MEMORY_SCOPE_AGENT);
}
__device__ __forceinline__ void ast4(unsigned short* p, unsigned int v) {
  __hip_atomic_store((unsigned int*)p, v, __ATOMIC_RELAXED, __HIP_MEMORY_SCOPE_AGENT);
}
__device__ __forceinline__ unsigned int aldf(const unsigned int* p) {
  return __hip_atomic_load(p, __ATOMIC_RELAXED, __HIP_MEMORY_SCOPE_AGENT);
}
__device__ __forceinline__ void astf(unsigned int* p, unsigned int v) {
  __hip_atomic_store(p, v, __ATOMIC_RELAXED, __HIP_MEMORY_SCOPE_AGENT);
}

__device__ __forceinline__ f32x4 mfma16(bf16x8 a, bf16x8 b, f32x4 c) {
  return __builtin_amdgcn_mfma_f32_16x16x32_bf16(a, b, c, 0, 0, 0);
}

// ---------------- fp32 -> bf16 conversion ----------------
__global__ __launch_bounds__(256) void cvt_kernel(const float* __restrict__ in,
                                                  unsigned short* __restrict__ out, int n) {
  const int stride = gridDim.x * blockDim.x * 4;
  for (int i = (blockIdx.x * blockDim.x + threadIdx.x) * 4; i < n; i += stride) {
    float4 v = *reinterpret_cast<const float4*>(in + i);
    ushort4 o;
    o.x = f2bf(v.x); o.y = f2bf(v.y); o.z = f2bf(v.z); o.w = f2bf(v.w);
    *reinterpret_cast<ushort4*>(out + i) = o;
  }
}

// ---------------- XP = x @ Wx.T + folded biases, bf16 block-tiled ----------------
__global__ __launch_bounds__(256) void xp_gemm_kernel(
    const unsigned short* __restrict__ xb,
    const unsigned short* __restrict__ Wxb,
    const float* __restrict__ bx,
    const float* __restrict__ bh,
    const float* __restrict__ bgh,
    unsigned short* __restrict__ XPb) {
  const int m0 = blockIdx.x * 64;
  const int n0 = blockIdx.y * 64;
  const int wave = threadIdx.x >> 6;
  const int lane = threadIdx.x & 63;
  const int l15 = lane & 15;
  const int lk = (lane >> 4) * 8;
  const int ro = (wave >> 1) * 32;
  const int co = (wave & 1) * 32;
  const unsigned short* ap = xb + (size_t)(m0 + ro + l15) * INn + lk;
  const unsigned short* bp = Wxb + (size_t)(n0 + co + l15) * INn + lk;
  f32x4 acc[2][2] = {};
  for (int k = 0; k < INn; k += 32) {
    bf16x8 a0 = ld8(ap + k);
    bf16x8 a1 = ld8(ap + 16 * INn + k);
    bf16x8 w0 = ld8(bp + k);
    bf16x8 w1 = ld8(bp + 16 * INn + k);
    acc[0][0] = mfma16(a0, w0, acc[0][0]);
    acc[0][1] = mfma16(a0, w1, acc[0][1]);
    acc[1][0] = mfma16(a1, w0, acc[1][0]);
    acc[1][1] = mfma16(a1, w1, acc[1][1]);
  }
#pragma unroll
  for (int rt = 0; rt < 2; ++rt)
#pragma unroll
    for (int ct = 0; ct < 2; ++ct) {
      const int col = n0 + co + ct * 16 + l15;
      const int gate = col >> 9, jcol = col & 511;
      const int jb = jcol >> 4, jl = jcol & 15;
      float bias = bx[col];
      if (col < 1024) bias += bh[col] + bgh[col];
      else if (col >= 1536) bias += bh[col - 512] + bgh[col - 512];
#pragma unroll
      for (int r = 0; r < 4; ++r) {
        const int row = m0 + ro + rt * 16 + (lane >> 4) * 4 + r;
        const int ttl = row >> 8, bb = row & 255;
        XPb[(((size_t)ttl * 8 + (bb >> 5)) * 32 + jb) * 2048 +
            gate * 512 + (bb & 31) * 16 + jl] = f2bf(acc[rt][ct][r] + bias);
      }
    }
}

// ---------------- persistent recurrence (X/Y pipelined, flag-gated) ----------------
// grp = blockIdx&7 (32 b-rows), jblk = blockIdx>>3 (16 j-cols). Producer flags
// PER GROUP (round-7 bug: groups shared one flag array -> cross-group races).
// Wave w gathers columns of source blocks 4w..4w+3 and polls only those flags.
__device__ __forceinline__ void poll_flags(const unsigned int* f, unsigned int ep,
                                           int jblk) {
  const int lane = threadIdx.x & 63;
  const int w = threadIdx.x >> 6;
  const int src = (w << 2) + ((lane & 7) >> 1);
  if (src == jblk) return;  // own data already drained at our last syncthreads
  const unsigned int* p = f + src;
  while (aldf(p) < ep) __builtin_amdgcn_s_sleep(1);
}

// gather 32 rows x 512 cols bf16 from LLC into swizzled LDS; wave w covers c=8w..8w+7
__device__ __forceinline__ void gather32(const unsigned short* src,
                                         unsigned short* dst, int b0) {
  const int lane = threadIdx.x & 63;
  const int w = threadIdx.x >> 6;
  const int c = (w << 3) + (lane & 7);
  const int r0 = (lane >> 3) << 2;
#pragma unroll
  for (int p = 0; p < 4; ++p) {
    const int rr = r0 + p;
    const unsigned short* s = src + (size_t)(b0 + rr) * Hn + c * 8;
    unsigned long long lo = ald8(s);
    unsigned long long hi = ald8(s + 4);
    char* d = (char*)dst + rr * 1024 + ((c * 16) ^ ((rr & 7) << 4));
    *(unsigned long long*)d = lo;
    *(unsigned long long*)(d + 8) = hi;
  }
}

__global__ __launch_bounds__(512, 1) void persist_kernel(
    const unsigned short* __restrict__ Whb,
    const unsigned short* __restrict__ Wghb,
    const unsigned short* __restrict__ Whdb,
    const unsigned short* __restrict__ Wgb,
    const unsigned short* __restrict__ XPb,
    const float* __restrict__ bhd,
    const float* __restrict__ bg,
    unsigned short* __restrict__ hb0,      // 2 ping-pong slots of 256*512
    unsigned short* __restrict__ gb,
    unsigned short* __restrict__ hdb,
    float* __restrict__ g_master,
    const float* __restrict__ h0,
    const float* __restrict__ g0,
    float* __restrict__ hs,
    float* __restrict__ h_tail,
    float* __restrict__ g_tail,
    unsigned int* __restrict__ slab,       // per grp: [grp*64 .. +31]=FH, [+32..+63]=FG
    int t0, int Tc) {
  __shared__ unsigned short Wh_l[48 * 512];   // 48KB swizzled Wh (z,r,u) slice
  __shared__ unsigned short As_h[32 * 512];   // 32KB: h(t)
  __shared__ unsigned short As_B[32 * 512];   // 32KB: g / hd
  __shared__ float pa[8][32][17];             // 17KB
  __shared__ unsigned short xp_ls[2][2048];   // 8KB XP double buffer

  const int tid = threadIdx.x;
  const int grp = blockIdx.x & 7;
  const int jblk = blockIdx.x >> 3;
  const int j0 = jblk * 16;
  const int b0 = grp * 32;
  const int wv = tid >> 6;
  const int lane = tid & 63;
  const int l15 = lane & 15;
  const int lk = (lane >> 4) * 8;
  unsigned int* FH = slab + grp * 64;        // <-- per-group (round-7 fix)
  unsigned int* FG = slab + grp * 64 + 32;

  // ---- stage Wh slice into LDS (swizzled), preload XP tile s=0 ----
  for (int i = tid; i < 48 * 64; i += TPB) {
    const int rr = i >> 6, c = i & 63;
    const int grow = (rr >> 4) * 512 + j0 + (rr & 15);
    const int byte = rr * 1024 + ((c * 16) ^ ((rr & 7) << 4));
    *reinterpret_cast<uint4*>(reinterpret_cast<char*>(Wh_l) + byte) =
        *reinterpret_cast<const uint4*>(Whb + (size_t)grow * 512 + c * 8);
  }
  {
    const unsigned short* src = XPb + ((size_t)grp * 32 + jblk) * 2048;
    *(unsigned long long*)&xp_ls[0][tid * 4] =
        *(const unsigned long long*)(src + tid * 4);
  }

  // ---- per-thread persistent state ----
  const int bl_e = tid >> 4, jl_e = tid & 15;
  const int j_e = j0 + jl_e;
  const size_t o_e = (size_t)(b0 + bl_e) * Hn + j_e;
  float h_m = (t0 == 0) ? h0[o_e] : hs[(size_t)(t0 - 1) * (Bn * Hn) + o_e];
  float g_m = (t0 == 0) ? g0[o_e] : g_master[o_e];
  const float bz2 = bhd[j_e] + bg[j_e];
  const float br2 = bhd[512 + j_e] + bg[512 + j_e];
  const float bgc = bhd[1024 + j_e];
  const int xo = bl_e * 16 + jl_e;
  const int swzA = (l15 & 7) << 4;
  float z2p = 0.0f, r2p = 0.0f;

  // ================= PROLOGUE: compute + publish h(t0), hd(t0) =================
  gather32(hb0 + (size_t)(t0 & 1) * (Bn * Hn), As_h, b0);   // h(t0-1)
  gather32(gb, As_B, b0);                                    // g(t0-1)
  __syncthreads();
  {  // 8-wave GEMM: wv0-2 Wh·h, wv3-5 Wgh·g, wv6-7 Wg·g
    const unsigned short* As = (wv < 3) ? As_h : As_B;
    const unsigned short* bp =
        (wv < 3) ? nullptr
        : (wv < 6) ? Wghb + (size_t)((wv - 3) * 512 + j0 + l15) * Hn + lk
                   : Wgb + (size_t)((wv - 6) * 512 + j0 + l15) * Hn + lk;
    const int wrow = wv * 16 + l15;
    f32x4 acc0 = {}, acc1 = {};
#pragma unroll
    for (int kt = 0; kt < 16; ++kt) {
      const int k2 = (kt * 32 + lk) * 2;
      const int abyte = k2 ^ swzA;
      bf16x8 a0 = *reinterpret_cast<const bf16x8*>(
          reinterpret_cast<const char*>(As) + l15 * 1024 + abyte);
      bf16x8 a1 = *reinterpret_cast<const bf16x8*>(
          reinterpret_cast<const char*>(As) + (16 + l15) * 1024 + abyte);
      bf16x8 bw = (wv < 3)
          ? *reinterpret_cast<const bf16x8*>(
                reinterpret_cast<const char*>(Wh_l) + wrow * 1024 + (k2 ^ ((wrow & 7) << 4)))
          : ld8(bp + kt * 32);
      acc0 = mfma16(a0, bw, acc0);
      acc1 = mfma16(a1, bw, acc1);
    }
#pragma unroll
    for (int r = 0; r < 4; ++r) {
      pa[wv][(lane >> 4) * 4 + r][l15] = acc0[r];
      pa[wv][16 + (lane >> 4) * 4 + r][l15] = acc1[r];
    }
  }
  __syncthreads();
  {  // h-update(t0)
    const float z = sigm(bf2f(xp_ls[0][xo]) + pa[0][bl_e][jl_e] + pa[3][bl_e][jl_e]);
    const float r = sigm(bf2f(xp_ls[0][512 + xo]) + pa[1][bl_e][jl_e] + pa[4][bl_e][jl_e]);
    const float u = sigm(bf2f(xp_ls[0][1536 + xo]) + pa[2][bl_e][jl_e] + pa[5][bl_e][jl_e]);
    const float cand = tanh_f(bf2f(xp_ls[0][1024 + xo]) + r * h_m + u * g_m);
    const float hn = (1.0f - z) * h_m + z * cand;
    const float hd = hn - h_m;
    hs[(size_t)t0 * (Bn * Hn) + o_e] = hn;
    const unsigned int hn_u = f2bf(hn), hd_u = f2bf(hd);
    const unsigned int hn_hi = (unsigned int)__shfl_down((int)hn_u, 1);
    const unsigned int hd_hi = (unsigned int)__shfl_down((int)hd_u, 1);
    if ((jl_e & 1) == 0) {
      ast4(hb0 + (size_t)((t0 + 1) & 1) * (Bn * Hn) + o_e, hn_u | (hn_hi << 16));
      ast4(hdb + o_e, hd_u | (hd_hi << 16));
    }
    z2p = pa[6][bl_e][jl_e];
    r2p = pa[7][bl_e][jl_e];
    h_m = hn;
  }
  __syncthreads();                      // drains publish stores (vmcnt0)
  if (tid == 0) astf(FH + jblk, 1u);    // h(t0), hd(t0) ready

  // ================= MAIN LOOP =================
  for (int tt = 0; tt < Tc; ++tt) {
    const int t = t0 + tt;

    // -------- X(tt): consume h(t), hd(t); produce g(t) --------
    poll_flags(FH, (unsigned int)(tt + 1), jblk);
    gather32(hb0 + (size_t)((t + 1) & 1) * (Bn * Hn), As_h, b0);  // h(t)
    gather32(hdb, As_B, b0);                                       // hd(t)
    __syncthreads();
    if (wv < 3) {        // Wh · h(t)  -> pa[0..2]  (for h-update(t+1))
      const int wrow = wv * 16 + l15;
      f32x4 acc0 = {}, acc1 = {};
#pragma unroll
      for (int kt = 0; kt < 16; ++kt) {
        const int k2 = (kt * 32 + lk) * 2;
        const int abyte = k2 ^ swzA;
        bf16x8 a0 = *reinterpret_cast<const bf16x8*>(
            reinterpret_cast<const char*>(As_h) + l15 * 1024 + abyte);
        bf16x8 a1 = *reinterpret_cast<const bf16x8*>(
            reinterpret_cast<const char*>(As_h) + (16 + l15) * 1024 + abyte);
        bf16x8 bw = *reinterpret_cast<const bf16x8*>(
            reinterpret_cast<const char*>(Wh_l) + wrow * 1024 + (k2 ^ ((wrow & 7) << 4)));
        acc0 = mfma16(a0, bw, acc0);
        acc1 = mfma16(a1, bw, acc1);
      }
#pragma unroll
      for (int r = 0; r < 4; ++r) {
        pa[wv][(lane >> 4) * 4 + r][l15] = acc0[r];
        pa[wv][16 + (lane >> 4) * 4 + r][l15] = acc1[r];
      }
    } else if (wv < 6) {  // Whd · hd(t) -> pa[3..5]  (z2, r2, gc)
      const unsigned short* bp = Whdb + (size_t)((wv - 3) * 512 + j0 + l15) * Hn + lk;
      f32x4 acc0 = {}, acc1 = {};
#pragma unroll
      for (int kt = 0; kt < 16; ++kt) {
        const int k2 = (kt * 32 + lk) * 2;
        const int abyte = k2 ^ swzA;
        bf16x8 a0 = *reinterpret_cast<const bf16x8*>(
            reinterpret_cast<const char*>(As_B) + l15 * 1024 + abyte);
        bf16x8 a1 = *reinterpret_cast<const bf16x8*>(
            reinterpret_cast<const char*>(As_B) + (16 + l15) * 1024 + abyte);
        bf16x8 bw = ld8(bp + kt * 32);
        acc0 = mfma16(a0, bw, acc0);
        acc1 = mfma16(a1, bw, acc1);
      }
#pragma unroll
      for (int r = 0; r < 4; ++r) {
        pa[wv][(lane >> 4) * 4 + r][l15] = acc0[r];
        pa[wv][16 + (lane >> 4) * 4 + r][l15] = acc1[r];
      }
    } else if (tt + 1 < Tc) {  // XP(t+1) prefetch (waves 6-7)
      const unsigned short* src =
          XPb + (((size_t)(tt + 1) * 8 + grp) * 32 + jblk) * 2048;
      for (int i = tid - 384; i < 512; i += 128)
        *(unsigned long long*)&xp_ls[(tt + 1) & 1][i * 4] =
            *(const unsigned long long*)(src + i * 4);
    }
    __syncthreads();
    {  // g-update(t)
      const float z2 = sigm(pa[3][bl_e][jl_e] + z2p + bz2);
      const float r2 = sigm(pa[4][bl_e][jl_e] + r2p + br2);
      const float gc = tanh_f(pa[5][bl_e][jl_e] + bgc + r2 * g_m);
      const float gn = (1.0f - z2) * g_m + z2 * gc;
      g_m = gn;
      if (t == Tn - 1) g_tail[o_e] = gn;
      const unsigned int gn_u = f2bf(gn);
      const unsigned int gn_hi = (unsigned int)__shfl_down((int)gn_u, 1);
      if ((jl_e & 1) == 0) ast4(gb + o_e, gn_u | (gn_hi << 16));
    }
    __syncthreads();
    if (tid == 0) astf(FG + jblk, (unsigned int)(tt + 1));

    if (tt + 1 >= Tc) break;  // last step: h(t+1) recomputed by next chunk's prologue

    // -------- Y(tt): consume g(t); produce h(t+1), hd(t+1) --------
    poll_flags(FG, (unsigned int)(tt + 1), jblk);
    gather32(gb, As_B, b0);
    __syncthreads();
    if (wv < 5) {  // wv0-2: Wgh·g -> pa[3..5]; wv3-4: Wg·g -> pa[6..7]
      const unsigned short* bp =
          (wv < 3) ? Wghb + (size_t)(wv * 512 + j0 + l15) * Hn + lk
                   : Wgb + (size_t)((wv - 3) * 512 + j0 + l15) * Hn + lk;
      f32x4 acc0 = {}, acc1 = {};
#pragma unroll
      for (int kt = 0; kt < 16; ++kt) {
        const int k2 = (kt * 32 + lk) * 2;
        const int abyte = k2 ^ swzA;
        bf16x8 a0 = *reinterpret_cast<const bf16x8*>(
            reinterpret_cast<const char*>(As_B) + l15 * 1024 + abyte);
        bf16x8 a1 = *reinterpret_cast<const bf16x8*>(
            reinterpret_cast<const char*>(As_B) + (16 + l15) * 1024 + abyte);
        bf16x8 bw = ld8(bp + kt * 32);
        acc0 = mfma16(a0, bw, acc0);
        acc1 = mfma16(a1, bw, acc1);
      }
#pragma unroll
      for (int r = 0; r < 4; ++r) {
        pa[3 + wv][(lane >> 4) * 4 + r][l15] = acc0[r];
        pa[3 + wv][16 + (lane >> 4) * 4 + r][l15] = acc1[r];
      }
    }
    __syncthreads();
    {  // h-update(t+1)
      const int xb_ = (tt + 1) & 1;
      const float z = sigm(bf2f(xp_ls[xb_][xo]) + pa[0][bl_e][jl_e] + pa[3][bl_e][jl_e]);
      const float r = sigm(bf2f(xp_ls[xb_][512 + xo]) + pa[1][bl_e][jl_e] + pa[4][bl_e][jl_e]);
      const float u = sigm(bf2f(xp_ls[xb_][1536 + xo]) + pa[2][bl_e][jl_e] + pa[5][bl_e][jl_e]);
      const float cand = tanh_f(bf2f(xp_ls[xb_][1024 + xo]) + r * h_m + u * g_m);
      const float hn = (1.0f - z) * h_m + z * cand;
      const float hd = hn - h_m;
      hs[(size_t)(t + 1) * (Bn * Hn) + o_e] = hn;
      if (t + 1 == Tn - 1) h_tail[o_e] = hn;
      const unsigned int hn_u = f2bf(hn), hd_u = f2bf(hd);
      const unsigned int hn_hi = (unsigned int)__shfl_down((int)hn_u, 1);
      const unsigned int hd_hi = (unsigned int)__shfl_down((int)hd_u, 1);
      if ((jl_e & 1) == 0) {
        ast4(hb0 + (size_t)(t & 1) * (Bn * Hn) + o_e, hn_u | (hn_hi << 16));
        ast4(hdb + o_e, hd_u | (hd_hi << 16));
      }
      z2p = pa[6][bl_e][jl_e];
      r2p = pa[7][bl_e][jl_e];
      h_m = hn;
    }
    __syncthreads();
    if (tid == 0) astf(FH + jblk, (unsigned int)(tt + 2));
  }
  g_master[o_e] = g_m;
}

// ---------------- host ----------------
extern "C" void kernel_launch(void* const* d_in, const int* in_sizes, int n_in,
                              void* d_out, int out_size, void* d_ws, size_t ws_size,
                              hipStream_t stream) {
  const float* x   = (const float*)d_in[0];
  const float* h0  = (const float*)d_in[1];
  const float* g0  = (const float*)d_in[2];
  const float* Wx  = (const float*)d_in[3];
  const float* bx  = (const float*)d_in[4];
  const float* Wh  = (const float*)d_in[5];
  const float* bh  = (const float*)d_in[6];
  const float* Wgh = (const float*)d_in[7];
  const float* bgh = (const float*)d_in[8];
  const float* Whd = (const float*)d_in[9];
  const float* bhd = (const float*)d_in[10];
  const float* Wg  = (const float*)d_in[11];
  const float* bg  = (const float*)d_in[12];

  char* ws = (char*)d_ws;
  unsigned short* Whb  = (unsigned short*)(ws + 0);
  unsigned short* Wghb = (unsigned short*)(ws + 1572864);
  unsigned short* Whdb = (unsigned short*)(ws + 3145728);
  unsigned short* Wgb  = (unsigned short*)(ws + 4718592);
  unsigned short* Wxb  = (unsigned short*)(ws + 5767168);
  unsigned short* hb0  = (unsigned short*)(ws + 7864320);   // 2 x 256x512
  unsigned short* gb_  = (unsigned short*)(ws + 8388608);
  unsigned short* hdb  = (unsigned short*)(ws + 8650752);
  float* g_master      = (float*)(ws + 8912896);
  unsigned int* flags  = (unsigned int*)(ws + 9437184);     // 16KB = 8 chunks x 512 uints
  const size_t FIXED = 9453568ULL;

  int Tc = 64;
  while (Tc > 1 && FIXED + (size_t)Tc * (262144ULL + 1048576ULL) > ws_size) Tc >>= 1;
  unsigned short* xb  = (unsigned short*)(ws + FIXED);
  unsigned short* XPb = (unsigned short*)(ws + FIXED + (size_t)Tc * 262144ULL);

  float* hs = (float*)d_out;
  float* h_tail = hs + (size_t)Tn * Bn * Hn;
  float* g_tail = h_tail + (size_t)Bn * Hn;

  hipMemsetAsync(flags, 0, 16384, stream);
  cvt_kernel<<<dim3(512), 256, 0, stream>>>(Wh, Whb, 1536 * 512);
  cvt_kernel<<<dim3(512), 256, 0, stream>>>(Wgh, Wghb, 1536 * 512);
  cvt_kernel<<<dim3(512), 256, 0, stream>>>(Whd, Whdb, 1536 * 512);
  cvt_kernel<<<dim3(512), 256, 0, stream>>>(Wg, Wgb, 1024 * 512);
  cvt_kernel<<<dim3(512), 256, 0, stream>>>(Wx, Wxb, 2048 * 512);
  cvt_kernel<<<dim3(128), 256, 0, stream>>>(h0, hb0, Bn * Hn);
  cvt_kernel<<<dim3(128), 256, 0, stream>>>(g0, gb_, Bn * Hn);

  const int nChunks = Tn / Tc;
  for (int c = 0; c < nChunks; ++c) {
    const int t0 = c * Tc;
    cvt_kernel<<<dim3(1024), 256, 0, stream>>>(x + (size_t)t0 * Bn * INn, xb,
                                               Tc * Bn * INn);
    xp_gemm_kernel<<<dim3(Tc * 4, 32), 256, 0, stream>>>(xb, Wxb, bx, bh, bgh, XPb);
    persist_kernel<<<dim3(256), dim3(TPB), 0, stream>>>(
        Whb, Wghb, Whdb, Wgb, XPb, bhd, bg, hb0, gb_, hdb, g_master, h0, g0,
        hs, h_tail, g_tail, flags + c * 512, t0, Tc);
  }
}

// Round 9
// 9634.785 us; speedup vs baseline: 1.0078x; 1.0078x over previous
//
#include <hip/hip_runtime.h>

#define Tn 512
#define Bn 256
#define Hn 512
#define INn 512
#define TPB 512

typedef __attribute__((ext_vector_type(8))) short bf16x8;
typedef __attribute__((ext_vector_type(4))) float f32x4;

__device__ __forceinline__ unsigned short f2bf(float f) {
  unsigned int u = __float_as_uint(f);
  unsigned int r = (u + 0x7fffu + ((u >> 16) & 1u)) >> 16;
  return (unsigned short)r;
}
__device__ __forceinline__ float bf2f(unsigned short u) {
  return __uint_as_float(((unsigned int)u) << 16);
}

__device__ __forceinline__ float sigm(float x) { return 1.0f / (1.0f + __expf(-x)); }
__device__ __forceinline__ float tanh_f(float x) { return 2.0f / (1.0f + __expf(-2.0f * x)) - 1.0f; }

__device__ __forceinline__ bf16x8 ld8(const unsigned short* p) {
  return *reinterpret_cast<const bf16x8*>(p);
}

// ---- agent-scope (LLC) relaxed ops — the ONLY cross-block medium (r3/r4/r8-proven) ----
__device__ __forceinline__ unsigned long long ald8(const unsigned short* p) {
  return __hip_atomic_load((const unsigned long long*)p, __ATOMIC_RELAXED,
                           __HIP_MEMORY_SCOPE_AGENT);
}
__device__ __forceinline__ void ast4(unsigned short* p, unsigned int v) {
  __hip_atomic_store((unsigned int*)p, v, __ATOMIC_RELAXED, __HIP_MEMORY_SCOPE_AGENT);
}
__device__ __forceinline__ unsigned int aldf(const unsigned int* p) {
  return __hip_atomic_load(p, __ATOMIC_RELAXED, __HIP_MEMORY_SCOPE_AGENT);
}
__device__ __forceinline__ void astf(unsigned int* p, unsigned int v) {
  __hip_atomic_store(p, v, __ATOMIC_RELAXED, __HIP_MEMORY_SCOPE_AGENT);
}

__device__ __forceinline__ f32x4 mfma16(bf16x8 a, bf16x8 b, f32x4 c) {
  return __builtin_amdgcn_mfma_f32_16x16x32_bf16(a, b, c, 0, 0, 0);
}

// ---------------- fp32 -> bf16 conversion ----------------
__global__ __launch_bounds__(256) void cvt_kernel(const float* __restrict__ in,
                                                  unsigned short* __restrict__ out, int n) {
  const int stride = gridDim.x * blockDim.x * 4;
  for (int i = (blockIdx.x * blockDim.x + threadIdx.x) * 4; i < n; i += stride) {
    float4 v = *reinterpret_cast<const float4*>(in + i);
    ushort4 o;
    o.x = f2bf(v.x); o.y = f2bf(v.y); o.z = f2bf(v.z); o.w = f2bf(v.w);
    *reinterpret_cast<ushort4*>(out + i) = o;
  }
}

// ---------------- in-persist XP tile: one wave computes one gate (16 cols x 32 rows) ----
// dst layout [gate(4)][bl(32)][jl(16)] bf16, matching xo = bl*16+jl reads.
__device__ __forceinline__ void xp_tile(const unsigned short* __restrict__ xb,
                                        const unsigned short* __restrict__ Wxb,
                                        unsigned short* dst, int tl, int b0,
                                        int j0, int gate, float biasv) {
  const int lane = threadIdx.x & 63;
  const int l15 = lane & 15;
  const int lk = (lane >> 4) * 8;
  const unsigned short* ap = xb + ((size_t)tl * Bn + b0 + l15) * INn + lk;
  const unsigned short* bp = Wxb + (size_t)(gate * 512 + j0 + l15) * INn + lk;
  f32x4 acc0 = {}, acc1 = {};
#pragma unroll
  for (int kt = 0; kt < 16; ++kt) {
    bf16x8 a0 = ld8(ap + kt * 32);
    bf16x8 a1 = ld8(ap + 16 * INn + kt * 32);
    bf16x8 bw = ld8(bp + kt * 32);
    acc0 = mfma16(a0, bw, acc0);
    acc1 = mfma16(a1, bw, acc1);
  }
#pragma unroll
  for (int r = 0; r < 4; ++r) {
    const int row = (lane >> 4) * 4 + r;
    dst[gate * 512 + row * 16 + l15] = f2bf(acc0[r] + biasv);
    dst[gate * 512 + (row + 16) * 16 + l15] = f2bf(acc1[r] + biasv);
  }
}

// gather 32 rows x 512 cols bf16 from LLC into swizzled LDS; wave w covers c=8w..8w+7
__device__ __forceinline__ void gather32(const unsigned short* src,
                                         unsigned short* dst, int b0) {
  const int lane = threadIdx.x & 63;
  const int w = threadIdx.x >> 6;
  const int c = (w << 3) + (lane & 7);
  const int r0 = (lane >> 3) << 2;
#pragma unroll
  for (int p = 0; p < 4; ++p) {
    const int rr = r0 + p;
    const unsigned short* s = src + (size_t)(b0 + rr) * Hn + c * 8;
    unsigned long long lo = ald8(s);
    unsigned long long hi = ald8(s + 4);
    char* d = (char*)dst + rr * 1024 + ((c * 16) ^ ((rr & 7) << 4));
    *(unsigned long long*)d = lo;
    *(unsigned long long*)(d + 8) = hi;
  }
}

// wave-local poll (8 waves, each covers its 4 gather-source blocks)
__device__ __forceinline__ void poll_flags(const unsigned int* f, unsigned int ep,
                                           int jblk) {
  const int lane = threadIdx.x & 63;
  const int w = threadIdx.x >> 6;
  const int src = (w << 2) + ((lane & 7) >> 1);
  if (src == jblk) return;
  const unsigned int* p = f + src;
  while (aldf(p) < ep) __builtin_amdgcn_s_sleep(1);
}

__global__ __launch_bounds__(512, 1) void persist_kernel(
    const unsigned short* __restrict__ Whb,
    const unsigned short* __restrict__ Wghb,
    const unsigned short* __restrict__ Whdb,
    const unsigned short* __restrict__ Wgb,
    const unsigned short* __restrict__ xb,     // (Tc,256,512) bf16, chunk-local
    const unsigned short* __restrict__ Wxb,    // (2048,512) bf16
    const float* __restrict__ bx,
    const float* __restrict__ bh,
    const float* __restrict__ bgh,
    const float* __restrict__ bhd,
    const float* __restrict__ bg,
    unsigned short* __restrict__ hb0,      // 2 ping-pong slots of 256*512
    unsigned short* __restrict__ gb,
    unsigned short* __restrict__ hdb,
    float* __restrict__ g_master,
    const float* __restrict__ h0,
    const float* __restrict__ g0,
    float* __restrict__ hs,
    float* __restrict__ h_tail,
    float* __restrict__ g_tail,
    unsigned int* __restrict__ slab,       // per grp: [grp*64..+31]=FH, [+32..+63]=FG
    int t0, int Tc) {
  __shared__ unsigned short Wh_l[48 * 512];   // 48KB swizzled Wh (z,r,u) slice
  __shared__ unsigned short As_h[32 * 512];   // 32KB: h(t)
  __shared__ unsigned short As_B[32 * 512];   // 32KB: g / hd
  __shared__ float pa[8][32][17];             // 17KB
  __shared__ unsigned short xp_ls[2][2048];   // 8KB XP double buffer (parity = local t&1)

  const int tid = threadIdx.x;
  const int grp = blockIdx.x & 7;
  const int jblk = blockIdx.x >> 3;
  const int j0 = jblk * 16;
  const int b0 = grp * 32;
  const int wv = tid >> 6;
  const int lane = tid & 63;
  const int l15 = lane & 15;
  const int lk = (lane >> 4) * 8;
  unsigned int* FH = slab + grp * 64;
  unsigned int* FG = slab + grp * 64 + 32;

  // ---- stage Wh slice into LDS (swizzled) ----
  for (int i = tid; i < 48 * 64; i += TPB) {
    const int rr = i >> 6, c = i & 63;
    const int grow = (rr >> 4) * 512 + j0 + (rr & 15);
    const int byte = rr * 1024 + ((c * 16) ^ ((rr & 7) << 4));
    *reinterpret_cast<uint4*>(reinterpret_cast<char*>(Wh_l) + byte) =
        *reinterpret_cast<const uint4*>(Whb + (size_t)grow * 512 + c * 8);
  }

  // ---- per-lane XP bias for this wave's gate (prologue wv&3; Y-phase wv-4 == wv&3) ----
  const int gx = wv & 3;
  const int jx = j0 + l15;
  float bxp = bx[gx * 512 + jx];
  if (gx == 0) bxp += bh[jx] + bgh[jx];
  else if (gx == 1) bxp += bh[512 + jx] + bgh[512 + jx];
  else if (gx == 3) bxp += bh[1024 + jx] + bgh[1024 + jx];

  // ---- prologue XP: wv0-3 -> XP(t0) buf0, wv4-7 -> XP(t0+1) buf1 ----
  if (wv < 4) xp_tile(xb, Wxb, &xp_ls[0][0], 0, b0, j0, gx, bxp);
  else if (Tc > 1) xp_tile(xb, Wxb, &xp_ls[1][0], 1, b0, j0, gx, bxp);

  // ---- per-thread persistent state ----
  const int bl_e = tid >> 4, jl_e = tid & 15;
  const int j_e = j0 + jl_e;
  const size_t o_e = (size_t)(b0 + bl_e) * Hn + j_e;
  float h_m = (t0 == 0) ? h0[o_e] : hs[(size_t)(t0 - 1) * (Bn * Hn) + o_e];
  float g_m = (t0 == 0) ? g0[o_e] : g_master[o_e];
  const float bz2 = bhd[j_e] + bg[j_e];
  const float br2 = bhd[512 + j_e] + bg[512 + j_e];
  const float bgc = bhd[1024 + j_e];
  const int xo = bl_e * 16 + jl_e;
  const int swzA = (l15 & 7) << 4;
  float z2p = 0.0f, r2p = 0.0f;

  // ================= PROLOGUE: compute + publish h(t0), hd(t0) =================
  gather32(hb0 + (size_t)(t0 & 1) * (Bn * Hn), As_h, b0);   // h(t0-1)
  gather32(gb, As_B, b0);                                    // g(t0-1)
  __syncthreads();
  {  // 8-wave GEMM: wv0-2 Wh·h, wv3-5 Wgh·g, wv6-7 Wg·g
    const unsigned short* As = (wv < 3) ? As_h : As_B;
    const unsigned short* bp =
        (wv < 3) ? nullptr
        : (wv < 6) ? Wghb + (size_t)((wv - 3) * 512 + j0 + l15) * Hn + lk
                   : Wgb + (size_t)((wv - 6) * 512 + j0 + l15) * Hn + lk;
    const int wrow = wv * 16 + l15;
    f32x4 acc0 = {}, acc1 = {};
#pragma unroll
    for (int kt = 0; kt < 16; ++kt) {
      const int k2 = (kt * 32 + lk) * 2;
      const int abyte = k2 ^ swzA;
      bf16x8 a0 = *reinterpret_cast<const bf16x8*>(
          reinterpret_cast<const char*>(As) + l15 * 1024 + abyte);
      bf16x8 a1 = *reinterpret_cast<const bf16x8*>(
          reinterpret_cast<const char*>(As) + (16 + l15) * 1024 + abyte);
      bf16x8 bw = (wv < 3)
          ? *reinterpret_cast<const bf16x8*>(
                reinterpret_cast<const char*>(Wh_l) + wrow * 1024 + (k2 ^ ((wrow & 7) << 4)))
          : ld8(bp + kt * 32);
      acc0 = mfma16(a0, bw, acc0);
      acc1 = mfma16(a1, bw, acc1);
    }
#pragma unroll
    for (int r = 0; r < 4; ++r) {
      pa[wv][(lane >> 4) * 4 + r][l15] = acc0[r];
      pa[wv][16 + (lane >> 4) * 4 + r][l15] = acc1[r];
    }
  }
  __syncthreads();
  {  // h-update(t0)
    const float z = sigm(bf2f(xp_ls[0][xo]) + pa[0][bl_e][jl_e] + pa[3][bl_e][jl_e]);
    const float r = sigm(bf2f(xp_ls[0][512 + xo]) + pa[1][bl_e][jl_e] + pa[4][bl_e][jl_e]);
    const float u = sigm(bf2f(xp_ls[0][1536 + xo]) + pa[2][bl_e][jl_e] + pa[5][bl_e][jl_e]);
    const float cand = tanh_f(bf2f(xp_ls[0][1024 + xo]) + r * h_m + u * g_m);
    const float hn = (1.0f - z) * h_m + z * cand;
    const float hd = hn - h_m;
    hs[(size_t)t0 * (Bn * Hn) + o_e] = hn;
    const unsigned int hn_u = f2bf(hn), hd_u = f2bf(hd);
    const unsigned int hn_hi = (unsigned int)__shfl_down((int)hn_u, 1);
    const unsigned int hd_hi = (unsigned int)__shfl_down((int)hd_u, 1);
    if ((jl_e & 1) == 0) {
      ast4(hb0 + (size_t)((t0 + 1) & 1) * (Bn * Hn) + o_e, hn_u | (hn_hi << 16));
      ast4(hdb + o_e, hd_u | (hd_hi << 16));
    }
    z2p = pa[6][bl_e][jl_e];
    r2p = pa[7][bl_e][jl_e];
    h_m = hn;
  }
  __syncthreads();                      // drains publish stores (vmcnt0)
  if (tid == 0) astf(FH + jblk, 1u);    // h(t0), hd(t0) ready

  // ================= MAIN LOOP =================
  for (int tt = 0; tt < Tc; ++tt) {
    const int t = t0 + tt;

    // -------- X(tt): consume h(t), hd(t); produce g(t) --------
    poll_flags(FH, (unsigned int)(tt + 1), jblk);
    gather32(hb0 + (size_t)((t + 1) & 1) * (Bn * Hn), As_h, b0);  // h(t)
    gather32(hdb, As_B, b0);                                       // hd(t)
    __syncthreads();
    if (wv < 3) {        // Wh · h(t)  -> pa[0..2]  (for h-update(t+1))
      const int wrow = wv * 16 + l15;
      f32x4 acc0 = {}, acc1 = {};
#pragma unroll
      for (int kt = 0; kt < 16; ++kt) {
        const int k2 = (kt * 32 + lk) * 2;
        const int abyte = k2 ^ swzA;
        bf16x8 a0 = *reinterpret_cast<const bf16x8*>(
            reinterpret_cast<const char*>(As_h) + l15 * 1024 + abyte);
        bf16x8 a1 = *reinterpret_cast<const bf16x8*>(
            reinterpret_cast<const char*>(As_h) + (16 + l15) * 1024 + abyte);
        bf16x8 bw = *reinterpret_cast<const bf16x8*>(
            reinterpret_cast<const char*>(Wh_l) + wrow * 1024 + (k2 ^ ((wrow & 7) << 4)));
        acc0 = mfma16(a0, bw, acc0);
        acc1 = mfma16(a1, bw, acc1);
      }
#pragma unroll
      for (int r = 0; r < 4; ++r) {
        pa[wv][(lane >> 4) * 4 + r][l15] = acc0[r];
        pa[wv][16 + (lane >> 4) * 4 + r][l15] = acc1[r];
      }
    } else if (wv < 6) {  // Whd · hd(t) -> pa[3..5]  (z2, r2, gc)
      const unsigned short* bp = Whdb + (size_t)((wv - 3) * 512 + j0 + l15) * Hn + lk;
      f32x4 acc0 = {}, acc1 = {};
#pragma unroll
      for (int kt = 0; kt < 16; ++kt) {
        const int k2 = (kt * 32 + lk) * 2;
        const int abyte = k2 ^ swzA;
        bf16x8 a0 = *reinterpret_cast<const bf16x8*>(
            reinterpret_cast<const char*>(As_B) + l15 * 1024 + abyte);
        bf16x8 a1 = *reinterpret_cast<const bf16x8*>(
            reinterpret_cast<const char*>(As_B) + (16 + l15) * 1024 + abyte);
        bf16x8 bw = ld8(bp + kt * 32);
        acc0 = mfma16(a0, bw, acc0);
        acc1 = mfma16(a1, bw, acc1);
      }
#pragma unroll
      for (int r = 0; r < 4; ++r) {
        pa[wv][(lane >> 4) * 4 + r][l15] = acc0[r];
        pa[wv][16 + (lane >> 4) * 4 + r][l15] = acc1[r];
      }
    }
    __syncthreads();
    {  // g-update(t)
      const float z2 = sigm(pa[3][bl_e][jl_e] + z2p + bz2);
      const float r2 = sigm(pa[4][bl_e][jl_e] + r2p + br2);
      const float gc = tanh_f(pa[5][bl_e][jl_e] + bgc + r2 * g_m);
      const float gn = (1.0f - z2) * g_m + z2 * gc;
      g_m = gn;
      if (t == Tn - 1) g_tail[o_e] = gn;
      const unsigned int gn_u = f2bf(gn);
      const unsigned int gn_hi = (unsigned int)__shfl_down((int)gn_u, 1);
      if ((jl_e & 1) == 0) ast4(gb + o_e, gn_u | (gn_hi << 16));
    }
    __syncthreads();
    if (tid == 0) astf(FG + jblk, (unsigned int)(tt + 1));

    if (tt + 1 >= Tc) break;  // last step: h(t+1) recomputed by next chunk's prologue

    // -------- Y(tt): consume g(t); produce h(t+1), hd(t+1); idle waves compute XP(t+2) ----
    if (wv < 4) {
      {  // poll: 4 waves cover 8 sources each
        const int src = (wv << 3) + (lane & 7);
        if (src != jblk) {
          const unsigned int* p = FG + src;
          while (aldf(p) < (unsigned int)(tt + 1)) __builtin_amdgcn_s_sleep(1);
        }
      }
      for (int p = 0; p < 8; ++p) {  // gather g: 256 threads x 8 chunks
        const int idx = tid + p * 256;
        const int rr = idx >> 6, c = idx & 63;
        const unsigned short* s = gb + (size_t)(b0 + rr) * Hn + c * 8;
        unsigned long long lo = ald8(s);
        unsigned long long hi = ald8(s + 4);
        char* d = (char*)As_B + rr * 1024 + ((c * 16) ^ ((rr & 7) << 4));
        *(unsigned long long*)d = lo;
        *(unsigned long long*)(d + 8) = hi;
      }
    } else if (tt + 2 < Tc) {  // XP(t+2) into buf[(tt)&1] (dead since h-update(t))
      xp_tile(xb, Wxb, &xp_ls[tt & 1][0], tt + 2, b0, j0, gx, bxp);
    }
    __syncthreads();
    if (wv < 3) {  // Wgh·g -> pa[3..5]
      const unsigned short* bp = Wghb + (size_t)(wv * 512 + j0 + l15) * Hn + lk;
      f32x4 acc0 = {}, acc1 = {};
#pragma unroll
      for (int kt = 0; kt < 16; ++kt) {
        const int k2 = (kt * 32 + lk) * 2;
        const int abyte = k2 ^ swzA;
        bf16x8 a0 = *reinterpret_cast<const bf16x8*>(
            reinterpret_cast<const char*>(As_B) + l15 * 1024 + abyte);
        bf16x8 a1 = *reinterpret_cast<const bf16x8*>(
            reinterpret_cast<const char*>(As_B) + (16 + l15) * 1024 + abyte);
        bf16x8 bw = ld8(bp + kt * 32);
        acc0 = mfma16(a0, bw, acc0);
        acc1 = mfma16(a1, bw, acc1);
      }
#pragma unroll
      for (int r = 0; r < 4; ++r) {
        pa[3 + wv][(lane >> 4) * 4 + r][l15] = acc0[r];
        pa[3 + wv][16 + (lane >> 4) * 4 + r][l15] = acc1[r];
      }
    } else if (wv == 3) {  // Wg·g both gates -> pa[6], pa[7]
      const unsigned short* bp0 = Wgb + (size_t)(j0 + l15) * Hn + lk;
      const unsigned short* bp1 = Wgb + (size_t)(512 + j0 + l15) * Hn + lk;
      f32x4 a00 = {}, a01 = {}, a10 = {}, a11 = {};
#pragma unroll
      for (int kt = 0; kt < 16; ++kt) {
        const int k2 = (kt * 32 + lk) * 2;
        const int abyte = k2 ^ swzA;
        bf16x8 a0 = *reinterpret_cast<const bf16x8*>(
            reinterpret_cast<const char*>(As_B) + l15 * 1024 + abyte);
        bf16x8 a1 = *reinterpret_cast<const bf16x8*>(
            reinterpret_cast<const char*>(As_B) + (16 + l15) * 1024 + abyte);
        bf16x8 w0 = ld8(bp0 + kt * 32);
        bf16x8 w1 = ld8(bp1 + kt * 32);
        a00 = mfma16(a0, w0, a00);
        a10 = mfma16(a1, w0, a10);
        a01 = mfma16(a0, w1, a01);
        a11 = mfma16(a1, w1, a11);
      }
#pragma unroll
      for (int r = 0; r < 4; ++r) {
        pa[6][(lane >> 4) * 4 + r][l15] = a00[r];
        pa[6][16 + (lane >> 4) * 4 + r][l15] = a10[r];
        pa[7][(lane >> 4) * 4 + r][l15] = a01[r];
        pa[7][16 + (lane >> 4) * 4 + r][l15] = a11[r];
      }
    }
    __syncthreads();
    {  // h-update(t+1)
      const int xb_ = (tt + 1) & 1;
      const float z = sigm(bf2f(xp_ls[xb_][xo]) + pa[0][bl_e][jl_e] + pa[3][bl_e][jl_e]);
      const float r = sigm(bf2f(xp_ls[xb_][512 + xo]) + pa[1][bl_e][jl_e] + pa[4][bl_e][jl_e]);
      const float u = sigm(bf2f(xp_ls[xb_][1536 + xo]) + pa[2][bl_e][jl_e] + pa[5][bl_e][jl_e]);
      const float cand = tanh_f(bf2f(xp_ls[xb_][1024 + xo]) + r * h_m + u * g_m);
      const float hn = (1.0f - z) * h_m + z * cand;
      const float hd = hn - h_m;
      hs[(size_t)(t + 1) * (Bn * Hn) + o_e] = hn;
      if (t + 1 == Tn - 1) h_tail[o_e] = hn;
      const unsigned int hn_u = f2bf(hn), hd_u = f2bf(hd);
      const unsigned int hn_hi = (unsigned int)__shfl_down((int)hn_u, 1);
      const unsigned int hd_hi = (unsigned int)__shfl_down((int)hd_u, 1);
      if ((jl_e & 1) == 0) {
        ast4(hb0 + (size_t)(t & 1) * (Bn * Hn) + o_e, hn_u | (hn_hi << 16));
        ast4(hdb + o_e, hd_u | (hd_hi << 16));
      }
      z2p = pa[6][bl_e][jl_e];
      r2p = pa[7][bl_e][jl_e];
      h_m = hn;
    }
    __syncthreads();
    if (tid == 0) astf(FH + jblk, (unsigned int)(tt + 2));
  }
  g_master[o_e] = g_m;
}

// ---------------- host ----------------
extern "C" void kernel_launch(void* const* d_in, const int* in_sizes, int n_in,
                              void* d_out, int out_size, void* d_ws, size_t ws_size,
                              hipStream_t stream) {
  const float* x   = (const float*)d_in[0];
  const float* h0  = (const float*)d_in[1];
  const float* g0  = (const float*)d_in[2];
  const float* Wx  = (const float*)d_in[3];
  const float* bx  = (const float*)d_in[4];
  const float* Wh  = (const float*)d_in[5];
  const float* bh  = (const float*)d_in[6];
  const float* Wgh = (const float*)d_in[7];
  const float* bgh = (const float*)d_in[8];
  const float* Whd = (const float*)d_in[9];
  const float* bhd = (const float*)d_in[10];
  const float* Wg  = (const float*)d_in[11];
  const float* bg  = (const float*)d_in[12];

  char* ws = (char*)d_ws;
  unsigned short* Whb  = (unsigned short*)(ws + 0);
  unsigned short* Wghb = (unsigned short*)(ws + 1572864);
  unsigned short* Whdb = (unsigned short*)(ws + 3145728);
  unsigned short* Wgb  = (unsigned short*)(ws + 4718592);
  unsigned short* Wxb  = (unsigned short*)(ws + 5767168);
  unsigned short* hb0  = (unsigned short*)(ws + 7864320);   // 2 x 256x512
  unsigned short* gb_  = (unsigned short*)(ws + 8388608);
  unsigned short* hdb  = (unsigned short*)(ws + 8650752);
  float* g_master      = (float*)(ws + 8912896);
  unsigned int* flags  = (unsigned int*)(ws + 9437184);     // 2KB used per launch
  const size_t FIXED = 9453568ULL;

  int Tc = 512;   // single launch if ws allows; halves until xb fits
  while (Tc > 1 && FIXED + (size_t)Tc * 262144ULL > ws_size) Tc >>= 1;
  unsigned short* xb = (unsigned short*)(ws + FIXED);  // (Tc,256,512) bf16

  float* hs = (float*)d_out;
  float* h_tail = hs + (size_t)Tn * Bn * Hn;
  float* g_tail = h_tail + (size_t)Bn * Hn;

  cvt_kernel<<<dim3(512), 256, 0, stream>>>(Wh, Whb, 1536 * 512);
  cvt_kernel<<<dim3(512), 256, 0, stream>>>(Wgh, Wghb, 1536 * 512);
  cvt_kernel<<<dim3(512), 256, 0, stream>>>(Whd, Whdb, 1536 * 512);
  cvt_kernel<<<dim3(512), 256, 0, stream>>>(Wg, Wgb, 1024 * 512);
  cvt_kernel<<<dim3(512), 256, 0, stream>>>(Wx, Wxb, 2048 * 512);
  cvt_kernel<<<dim3(128), 256, 0, stream>>>(h0, hb0, Bn * Hn);
  cvt_kernel<<<dim3(128), 256, 0, stream>>>(g0, gb_, Bn * Hn);

  const int nChunks = Tn / Tc;
  for (int c = 0; c < nChunks; ++c) {
    const int t0 = c * Tc;
    hipMemsetAsync(flags, 0, 2048, stream);
    cvt_kernel<<<dim3(2048), 256, 0, stream>>>(x + (size_t)t0 * Bn * INn, xb,
                                               Tc * Bn * INn);
    persist_kernel<<<dim3(256), dim3(TPB), 0, stream>>>(
        Whb, Wghb, Whdb, Wgb, xb, Wxb, bx, bh, bgh, bhd, bg, hb0, gb_, hdb,
        g_master, h0, g0, hs, h_tail, g_tail, flags, t0, Tc);
  }
}